// Round 12
// baseline (171.211 us; speedup 1.0000x reference)
//
#include <hip/hip_runtime.h>
#include <math.h>

// Problem constants
#define BB   8
#define SS   100
#define TT   1200        // S * DMAX
#define NM   80          // NMEL
#define DMC  128         // DM
#define KK   9
#define G3   384         // 3*DM
#define NROW (BB*TT)     // 9600

typedef __attribute__((ext_vector_type(8))) short short8;
typedef __attribute__((ext_vector_type(4))) float f32x4;

__device__ __forceinline__ float sigmoid_(float v) { return 1.f / (1.f + __expf(-v)); }
__device__ __forceinline__ float tanh_(float v) {
    float a = fabsf(v);
    float e = __expf(-2.f * a);
    float t = (1.f - e) / (1.f + e);
    return copysignf(t, v);
}
__device__ __forceinline__ unsigned short f2bf(float f) {   // RNE fp32->bf16
    unsigned int u = __float_as_uint(f);
    unsigned int r = (u + 0x7fffu + ((u >> 16) & 1u)) >> 16;
    return (unsigned short)r;
}

// ---------------------------------------------------------------------------
// Kernel P (fused prep), 22 blocks x 1024 thr (unchanged).
// ---------------------------------------------------------------------------
__global__ __launch_bounds__(1024) void k_prep(
    const float* __restrict__ whf, const float* __restrict__ whb,
    const float* __restrict__ wif, const float* __restrict__ wib,
    const float* __restrict__ bf, const float* __restrict__ bbv,
    const int* __restrict__ dur,
    unsigned short* __restrict__ wph, unsigned short* __restrict__ wpl,
    unsigned short* __restrict__ wih_h, unsigned short* __restrict__ wih_l,
    float* __restrict__ biasc, int* __restrict__ starts) {
    int blk = blockIdx.x;
    int tid = threadIdx.x;
    if (blk < 12) {
        int idx = blk * 1024 + tid;           // [0, 12288)
        int lane = idx & 63;
        int k32  = (idx >> 6) & 3;
        int tau  = (idx >> 8) % 24;
        int dir  = idx / (24 * 4 * 64);
        const float* w = dir ? whb : whf;
        int g = tau * 16 + (lane & 15);
        int kbase = k32 * 32 + (lane >> 4) * 8;
#pragma unroll
        for (int j = 0; j < 8; j++) {
            float v = w[g * DMC + kbase + j];
            unsigned short hi = f2bf(v);
            float hif = __uint_as_float(((unsigned)hi) << 16);
            unsigned short lo = f2bf(v - hif);
            wph[idx * 8 + j] = hi;
            wpl[idx * 8 + j] = lo;
        }
    } else if (blk < 21) {
        int idx = (blk - 12) * 1024 + tid;    // [0, 9216)
        int lane = idx & 63;
        int ks   = (idx >> 6) % 3;
        int tau  = idx / (3 * 64);            // 0..47 ; dir = tau>=24
        int gate = tau * 16 + (lane & 15);
        int kb   = ks * 32 + (lane >> 4) * 8;
        const float* w = (gate < G3) ? (wif + gate * NM) : (wib + (gate - G3) * NM);
#pragma unroll
        for (int j = 0; j < 8; j++) {
            int k = kb + j;
            float v = (k < NM) ? w[k] : 0.f;
            unsigned short hi = f2bf(v);
            float hif = __uint_as_float(((unsigned)hi) << 16);
            unsigned short lo = f2bf(v - hif);
            wih_h[idx * 8 + j] = hi;
            wih_l[idx * 8 + j] = lo;
        }
    } else {
        __shared__ int buf[BB][128];
        int s = tid & 127, b = tid >> 7;
        int v = (s < SS) ? dur[b * SS + s] : 0;
        buf[b][s] = v;
        __syncthreads();
        for (int off = 1; off < 128; off <<= 1) {
            int t = (s >= off) ? buf[b][s - off] : 0;
            __syncthreads();
            buf[b][s] += t;
            __syncthreads();
        }
        if (s < SS) starts[b * SS + s] = buf[b][s] - v;
        if (tid < 768) biasc[tid] = (tid < G3) ? bf[tid] : bbv[tid - G3];
    }
}

// ---------------------------------------------------------------------------
// Kernel A: fused conv1+BN/ReLU+conv2+BN/ReLU — R7 scalar body (proven 50.7us,
// VGPR 52, no spill). R12: takes a t-offset so it can be launched as two
// half-grid dispatches (~26us each) -> k_gru becomes visible in rocprof top-5.
// ---------------------------------------------------------------------------
__global__ __launch_bounds__(256) void k_conv(
    const float* __restrict__ mel, const int* __restrict__ mel_len,
    const float* __restrict__ w1, const float* __restrict__ g1, const float* __restrict__ be1,
    const float* __restrict__ w2, const float* __restrict__ g2, const float* __restrict__ be2,
    float* __restrict__ xout, int toff) {
    int b = blockIdx.y;
    int t = blockIdx.x + toff;
    int ml = mel_len[b];
    if (t >= ml) return;

    __shared__ __align__(16) float mp[96];          // mp[i] = mel[i-8], i in [8,88)
    __shared__ __align__(16) float part[8][84];     // octet partials

    int tid = threadIdx.x;
    int mq = tid >> 6, g = tid & 63;
    int ms = 20 * mq;
    const float inv_sqrt = 0.9999950000374997f;     // 1/sqrt(1+1e-5)

    if (tid < 96) {
        float v = 0.f;
        if (tid >= 8 && tid < 88) v = mel[(b * TT + t) * NM + tid - 8];
        mp[tid] = v;
    }
    __syncthreads();

    float c[20];
#pragma unroll
    for (int m = 0; m < 20; m++) c[m] = 0.f;

#pragma unroll 1
    for (int dd = 0; dd < 2; dd++) {
        int d = g + 64 * dd;
        float sc = g1[d] * inv_sqrt;
        float w1r[KK], w2r[KK];
#pragma unroll
        for (int k = 0; k < KK; k++) { w1r[k] = w1[d * KK + k] * sc; w2r[k] = w2[d * KK + k]; }
        float sb = be1[d];

        float mw[12];
        {
            const float4* p4 = (const float4*)(mp + ms);
            float4 a = p4[0], bq = p4[1], cq = p4[2];
            mw[0]=a.x;  mw[1]=a.y;  mw[2]=a.z;  mw[3]=a.w;
            mw[4]=bq.x; mw[5]=bq.y; mw[6]=bq.z; mw[7]=bq.w;
            mw[8]=cq.x; mw[9]=cq.y; mw[10]=cq.z; mw[11]=cq.w;
        }
#pragma unroll
        for (int ch = 0; ch < 7; ch++) {
#pragma unroll
            for (int jj = 0; jj < 4; jj++) {
                int off = ch * 4 + jj;
                float yv = sb;
#pragma unroll
                for (int k = 0; k < KK; k++) yv = fmaf(w1r[k], mw[jj + k], yv);
                yv = fmaxf(yv, 0.f);
                int j = ms + off;
                if (j < 4 || j >= 84) yv = 0.f;
#pragma unroll
                for (int k = 0; k < KK; k++) {
                    int mo = off - k;
                    if (mo >= 0 && mo < 20) c[mo] = fmaf(w2r[k], yv, c[mo]);
                }
            }
            if (ch < 6) {
#pragma unroll
                for (int q = 0; q < 8; q++) mw[q] = mw[q + 4];
                const float4* p4 = (const float4*)(mp + ms + ch * 4 + 12);
                float4 a = p4[0];
                mw[8]=a.x; mw[9]=a.y; mw[10]=a.z; mw[11]=a.w;
            }
        }
    }

#pragma unroll
    for (int m = 0; m < 20; m++) {
        c[m] += __shfl_xor(c[m], 1);
        c[m] += __shfl_xor(c[m], 2);
        c[m] += __shfl_xor(c[m], 4);
    }
    if ((g & 7) == 0) {
        int p = g >> 3;
#pragma unroll
        for (int m = 0; m < 20; m += 4)
            *(float4*)&part[p][ms + m] = make_float4(c[m], c[m+1], c[m+2], c[m+3]);
    }
    __syncthreads();

    if (tid < 80) {
        float s = 0.f;
#pragma unroll
        for (int p = 0; p < 8; p++) s += part[p][tid];
        float v = fmaxf(0.f, fmaf(s, g2[0] * inv_sqrt, be2[0]));
        xout[(b * TT + t) * NM + tid] = v;
    }
}

// ---------------------------------------------------------------------------
// Kernel C (R12): fused projection+GRU.
//  - x B-frags pre-staged for all 12 iters (as R11), but with float4 loads
//    (2 dwordx4 per task instead of 8 scalar dwords).
//  - out-store hoisted OUT of the loop (h freezes after i=sd-1) -> no global
//    store inside the loop -> no per-iteration vmcnt(0) drain at the barrier.
// ---------------------------------------------------------------------------
__global__ __launch_bounds__(512, 2) void k_gru(
    const float* __restrict__ x,
    const unsigned short* __restrict__ wph, const unsigned short* __restrict__ wpl,
    const unsigned short* __restrict__ wih_h, const unsigned short* __restrict__ wih_l,
    const float* __restrict__ biasc,
    const int* __restrict__ dur_all, const int* __restrict__ starts,
    const int* __restrict__ src_len,
    const float* __restrict__ bhf, const float* __restrict__ bhb,
    float* __restrict__ out) {
    int sblk = blockIdx.x;   // 0..6
    int b    = blockIdx.y;   // 0..7
    int dir  = blockIdx.z;   // 0 fwd, 1 bwd
    int s0 = sblk * 16;

    __shared__ __align__(16) short8 xbh[12][192];           // x B-frags hi, all iters
    __shared__ __align__(16) short8 xbl[12][192];           // x B-frags lo
    __shared__ __align__(16) unsigned short hbh[2][2048];   // h B-frags hi (pp)
    __shared__ __align__(16) unsigned short hbl[2][2048];   // h B-frags lo (pp)
    __shared__ int sdur[16], sstart[16];

    int tid  = threadIdx.x;
    int wave = tid >> 6, lane = tid & 63;
    int quad = lane >> 4, seg = lane & 15;

    if (tid < 16) {
        int ss = s0 + tid;
        sdur[tid]   = (ss < SS) ? dur_all[b * SS + ss] : 0;
        sstart[tid] = (ss < SS) ? starts[b * SS + ss]  : 0;
    }
    for (int i = tid; i < 2048; i += 512) { hbh[0][i] = 0; hbl[0][i] = 0; }

    // ---- w_hh A-frags (taus wave, wave+8, wave+16), persist in regs ----
    short8 Ah[3][4], Al[3][4];
    const short8* wph8 = (const short8*)wph;
    const short8* wpl8 = (const short8*)wpl;
#pragma unroll
    for (int tt = 0; tt < 3; tt++)
#pragma unroll
        for (int k32 = 0; k32 < 4; k32++) {
            int idx = ((dir * 24 + wave + 8 * tt) * 4 + k32) * 64 + lane;
            Ah[tt][k32] = wph8[idx];
            Al[tt][k32] = wpl8[idx];
        }
    // ---- w_ih A-frags (same taus, K=96), persist in regs ----
    short8 Gh[3][3], Gl[3][3];
    const short8* wih_h8 = (const short8*)wih_h;
    const short8* wih_l8 = (const short8*)wih_l;
#pragma unroll
    for (int tt = 0; tt < 3; tt++)
#pragma unroll
        for (int ks = 0; ks < 3; ks++) {
            int idx = ((dir * 24 + wave + 8 * tt) * 3 + ks) * 64 + lane;
            Gh[tt][ks] = wih_h8[idx];
            Gl[tt][ks] = wih_l8[idx];
        }

    // ---- per-lane meta & biases ----
    int s = s0 + seg;
    int sd = (s < SS) ? dur_all[b * SS + s] : 0;
    int slb = src_len[b];
    const float* bih = biasc + dir * G3;
    const float* bhh = dir ? bhb : bhf;
    int j0 = wave * 16 + quad * 4;
    float4 i_r = *(const float4*)&bih[j0];
    float4 i_z = *(const float4*)&bih[DMC + j0];
    float4 bxn = *(const float4*)&bih[2 * DMC + j0];
    float4 h_r = *(const float4*)&bhh[j0];
    float4 h_z = *(const float4*)&bhh[DMC + j0];
    float4 bhn = *(const float4*)&bhh[2 * DMC + j0];
    float4 br = make_float4(i_r.x + h_r.x, i_r.y + h_r.y, i_r.z + h_r.z, i_r.w + h_r.w);
    float4 bz = make_float4(i_z.x + h_z.x, i_z.y + h_z.y, i_z.z + h_z.z, i_z.w + h_z.w);
    float4 h = make_float4(0.f, 0.f, 0.f, 0.f);

    int idx8 = (j0 >> 5) * 64 + ((j0 >> 3) & 3) * 16 + seg;
    int wbase = idx8 * 8 + (j0 & 7);             // h-frag write addr (shorts)

    __syncthreads();   // sdur/sstart + h[0] frags visible

    // ---- stage ALL x B-frags (12 iters x 192 frag-lanes), float4 loads ----
#pragma unroll
    for (int q = 0; q < 5; q++) {
        int u = tid + q * 512;
        if (u < 12 * 192) {
            int it  = u / 192;
            int rem = u - it * 192;
            int ks = rem >> 6, ln = rem & 63;
            int sg = ln & 15, qq = ln >> 4;
            int kb = ks * 32 + qq * 8;
            short8 hi8 = {0,0,0,0,0,0,0,0}, lo8 = {0,0,0,0,0,0,0,0};
            int d2 = sdur[sg];
            if (kb < NM && it < d2) {
                int t = dir ? (sstart[sg] + d2 - 1 - it) : (sstart[sg] + it);
                const float4* xr4 = (const float4*)(x + (size_t)(b * TT + t) * NM + kb);
                float4 va = xr4[0], vb = xr4[1];
                float vv[8] = {va.x, va.y, va.z, va.w, vb.x, vb.y, vb.z, vb.w};
#pragma unroll
                for (int j = 0; j < 8; j++) {
                    unsigned short hi = f2bf(vv[j]);
                    hi8[j] = (short)hi;
                    lo8[j] = (short)f2bf(vv[j] - __uint_as_float(((unsigned)hi) << 16));
                }
            }
            xbh[it][rem] = hi8;
            xbl[it][rem] = lo8;
        }
    }
    __syncthreads();

    for (int i = 0; i < 12; i++) {
        int p = i & 1;
        bool act = (i < sd);

        // ---- MFMA: 6 independent accumulator chains ----
        f32x4 axr = (f32x4){0.f,0.f,0.f,0.f};
        f32x4 axz = (f32x4){0.f,0.f,0.f,0.f};
        f32x4 axn = (f32x4){0.f,0.f,0.f,0.f};
        f32x4 ahr = (f32x4){0.f,0.f,0.f,0.f};
        f32x4 ahz = (f32x4){0.f,0.f,0.f,0.f};
        f32x4 ahn = (f32x4){0.f,0.f,0.f,0.f};
#pragma unroll
        for (int ks = 0; ks < 3; ks++) {
            short8 Bxh = xbh[i][ks * 64 + lane];
            short8 Bxl = xbl[i][ks * 64 + lane];
            axr = __builtin_amdgcn_mfma_f32_16x16x32_bf16(Gh[0][ks], Bxh, axr, 0, 0, 0);
            axr = __builtin_amdgcn_mfma_f32_16x16x32_bf16(Gh[0][ks], Bxl, axr, 0, 0, 0);
            axr = __builtin_amdgcn_mfma_f32_16x16x32_bf16(Gl[0][ks], Bxh, axr, 0, 0, 0);
            axz = __builtin_amdgcn_mfma_f32_16x16x32_bf16(Gh[1][ks], Bxh, axz, 0, 0, 0);
            axz = __builtin_amdgcn_mfma_f32_16x16x32_bf16(Gh[1][ks], Bxl, axz, 0, 0, 0);
            axz = __builtin_amdgcn_mfma_f32_16x16x32_bf16(Gl[1][ks], Bxh, axz, 0, 0, 0);
            axn = __builtin_amdgcn_mfma_f32_16x16x32_bf16(Gh[2][ks], Bxh, axn, 0, 0, 0);
            axn = __builtin_amdgcn_mfma_f32_16x16x32_bf16(Gh[2][ks], Bxl, axn, 0, 0, 0);
            axn = __builtin_amdgcn_mfma_f32_16x16x32_bf16(Gl[2][ks], Bxh, axn, 0, 0, 0);
        }
#pragma unroll
        for (int k32 = 0; k32 < 4; k32++) {
            short8 Bh = ((const short8*)hbh[p])[k32 * 64 + lane];
            short8 Bl = ((const short8*)hbl[p])[k32 * 64 + lane];
            ahr = __builtin_amdgcn_mfma_f32_16x16x32_bf16(Ah[0][k32], Bh, ahr, 0, 0, 0);
            ahr = __builtin_amdgcn_mfma_f32_16x16x32_bf16(Ah[0][k32], Bl, ahr, 0, 0, 0);
            ahr = __builtin_amdgcn_mfma_f32_16x16x32_bf16(Al[0][k32], Bh, ahr, 0, 0, 0);
            ahz = __builtin_amdgcn_mfma_f32_16x16x32_bf16(Ah[1][k32], Bh, ahz, 0, 0, 0);
            ahz = __builtin_amdgcn_mfma_f32_16x16x32_bf16(Ah[1][k32], Bl, ahz, 0, 0, 0);
            ahz = __builtin_amdgcn_mfma_f32_16x16x32_bf16(Al[1][k32], Bh, ahz, 0, 0, 0);
            ahn = __builtin_amdgcn_mfma_f32_16x16x32_bf16(Ah[2][k32], Bh, ahn, 0, 0, 0);
            ahn = __builtin_amdgcn_mfma_f32_16x16x32_bf16(Ah[2][k32], Bl, ahn, 0, 0, 0);
            ahn = __builtin_amdgcn_mfma_f32_16x16x32_bf16(Al[2][k32], Bh, ahn, 0, 0, 0);
        }

        // ---- lane-local GRU update (no global store in-loop) ----
        if (act) {
            float hv[4]  = {h.x, h.y, h.z, h.w};
            float brv[4] = {br.x, br.y, br.z, br.w};
            float bzv[4] = {bz.x, bz.y, bz.z, bz.w};
            float bxv[4] = {bxn.x, bxn.y, bxn.z, bxn.w};
            float bhv[4] = {bhn.x, bhn.y, bhn.z, bhn.w};
#pragma unroll
            for (int cmp = 0; cmp < 4; cmp++) {
                float r = sigmoid_(axr[cmp] + ahr[cmp] + brv[cmp]);
                float z = sigmoid_(axz[cmp] + ahz[cmp] + bzv[cmp]);
                float n = tanh_(axn[cmp] + bxv[cmp] + r * (ahn[cmp] + bhv[cmp]));
                hv[cmp] = (1.f - z) * n + z * hv[cmp];
            }
            h = make_float4(hv[0], hv[1], hv[2], hv[3]);
        }

        // ---- write h frags (split-bf16) to the other buffer ----
        {
            float hv[4] = {h.x, h.y, h.z, h.w};
            unsigned short hs_[4], ls_[4];
#pragma unroll
            for (int cmp = 0; cmp < 4; cmp++) {
                unsigned short hi = f2bf(hv[cmp]);
                float hif = __uint_as_float(((unsigned)hi) << 16);
                hs_[cmp] = hi;
                ls_[cmp] = f2bf(hv[cmp] - hif);
            }
            *(ushort4*)&hbh[1 - p][wbase] = make_ushort4(hs_[0], hs_[1], hs_[2], hs_[3]);
            *(ushort4*)&hbl[1 - p][wbase] = make_ushort4(ls_[0], ls_[1], ls_[2], ls_[3]);
        }
        __syncthreads();
    }

    // ---- single post-loop output store (h frozen since i = sd-1) ----
    if (sd > 0) {
        float4 vout = (s < slb) ? h : make_float4(0.f, 0.f, 0.f, 0.f);
        *(float4*)&out[(b * SS + s) * (2 * DMC) + dir * DMC + j0] = vout;
    }
}

// ---------------------------------------------------------------------------
extern "C" void kernel_launch(void* const* d_in, const int* in_sizes, int n_in,
                              void* d_out, int out_size, void* d_ws, size_t ws_size,
                              hipStream_t stream) {
    const float* mel      = (const float*)d_in[0];
    const int*   durations= (const int*)  d_in[1];
    const int*   mel_len  = (const int*)  d_in[2];
    const int*   src_len  = (const int*)  d_in[3];
    const float* w1       = (const float*)d_in[4];
    const float* g1       = (const float*)d_in[5];
    const float* be1      = (const float*)d_in[6];
    const float* w2       = (const float*)d_in[7];
    const float* g2       = (const float*)d_in[8];
    const float* be2      = (const float*)d_in[9];
    const float* w_ih_f   = (const float*)d_in[10];
    const float* w_hh_f   = (const float*)d_in[11];
    const float* b_ih_f   = (const float*)d_in[12];
    const float* b_hh_f   = (const float*)d_in[13];
    const float* w_ih_b   = (const float*)d_in[14];
    const float* w_hh_b   = (const float*)d_in[15];
    const float* b_ih_b   = (const float*)d_in[16];
    const float* b_hh_b   = (const float*)d_in[17];
    float* out = (float*)d_out;

    // workspace: x | wph | wpl | wih_h | wih_l | biasc | starts
    float* x    = (float*)d_ws;
    unsigned short* wph   = (unsigned short*)(x + NROW * NM);
    unsigned short* wpl   = wph + 2 * 24 * 4 * 64 * 8;
    unsigned short* wih_h = wpl + 2 * 24 * 4 * 64 * 8;
    unsigned short* wih_l = wih_h + 48 * 3 * 64 * 8;
    float* biasc = (float*)(wih_l + 48 * 3 * 64 * 8);
    int*   starts= (int*)(biasc + 768);

    k_prep<<<22, 1024, 0, stream>>>(w_hh_f, w_hh_b, w_ih_f, w_ih_b, b_ih_f, b_ih_b,
                                    durations, wph, wpl, wih_h, wih_l, biasc, starts);
    // two half-grids: makes k_gru visible in rocprof top-5 (diagnostic)
    k_conv<<<dim3(TT / 2, BB), 256, 0, stream>>>(mel, mel_len, w1, g1, be1, w2, g2, be2, x, 0);
    k_conv<<<dim3(TT / 2, BB), 256, 0, stream>>>(mel, mel_len, w1, g1, be1, w2, g2, be2, x, TT / 2);
    k_gru<<<dim3(7, 8, 2), 512, 0, stream>>>(x, wph, wpl, wih_h, wih_l, biasc,
                                             durations, starts, src_len,
                                             b_hh_f, b_hh_b, out);
}